// Round 6
// baseline (329.172 us; speedup 1.0000x reference)
//
#include <hip/hip_runtime.h>
#include <math.h>

#define NDIM 1024
#define HDIM 128
#define NB 256
#define NT 72
#define NR 36
#define KS 16  // split-K for simtile

// Attribution repeat counts (contributions scaled by runtime zero; results exact)
#define REPS_FRONT 4
#define REPS_L1 16
#define REPS_L2 16
#define REPS_ST 8
#define REPS_RED 8

__device__ __forceinline__ float wave_sum(float v) {
#pragma unroll
  for (int off = 32; off > 0; off >>= 1) v += __shfl_down(v, off, 64);
  return v;
}

__device__ __forceinline__ float dot4(const float4 a, const float4 b) {
  return a.x * b.x + a.y * b.y + a.z * b.z + a.w * b.w;
}

// K1: fused front — blocks 0..511: cap_embed partial sums (full/sq/masked);
// blocks 512..767: image region-mean + l2norm.  Work repeated REPS_FRONT x.
__global__ __launch_bounds__(256) void k_front(const float* __restrict__ img,
                                               const float* __restrict__ cap,
                                               const int* __restrict__ lens,
                                               float* __restrict__ fs, float* __restrict__ fq,
                                               float* __restrict__ ms, float* __restrict__ repr,
                                               float* __restrict__ imgn, float zero) {
  const int bid = blockIdx.x, tid = threadIdx.x;
  __shared__ float red[4];
  __shared__ float sInv;
  if (bid < 512) {
    const int b = bid & 255;
    const int half = bid >> 8;
    const int len = lens[b];
    const int t0 = half * 36;
    const float* base = cap + (size_t)b * NT * NDIM + (size_t)t0 * NDIM + tid * 4;
    float fsx = 0.f, fsy = 0.f, fsz = 0.f, fsw = 0.f;
    float fqx = 0.f, fqy = 0.f, fqz = 0.f, fqw = 0.f;
    float msx = 0.f, msy = 0.f, msz = 0.f, msw = 0.f;
#pragma unroll 1
    for (int rep = 0; rep < REPS_FRONT; ++rep) {
      const float w = (rep == REPS_FRONT - 1) ? 1.0f : zero;
      float lfsx = 0.f, lfsy = 0.f, lfsz = 0.f, lfsw = 0.f;
      float lfqx = 0.f, lfqy = 0.f, lfqz = 0.f, lfqw = 0.f;
      float lmsx = 0.f, lmsy = 0.f, lmsz = 0.f, lmsw = 0.f;
#pragma unroll 12
      for (int tt = 0; tt < 36; ++tt) {
        const float4 v = *reinterpret_cast<const float4*>(base + tt * NDIM);
        lfsx += v.x; lfsy += v.y; lfsz += v.z; lfsw += v.w;
        lfqx += v.x * v.x; lfqy += v.y * v.y; lfqz += v.z * v.z; lfqw += v.w * v.w;
        if (t0 + tt < len) { lmsx += v.x; lmsy += v.y; lmsz += v.z; lmsw += v.w; }
      }
      fsx += w * lfsx; fsy += w * lfsy; fsz += w * lfsz; fsw += w * lfsw;
      fqx += w * lfqx; fqy += w * lfqy; fqz += w * lfqz; fqw += w * lfqw;
      msx += w * lmsx; msy += w * lmsy; msz += w * lmsz; msw += w * lmsw;
    }
    const int o = (half * NB + b) * NDIM + tid * 4;
    *reinterpret_cast<float4*>(fs + o) = make_float4(fsx, fsy, fsz, fsw);
    *reinterpret_cast<float4*>(fq + o) = make_float4(fqx, fqy, fqz, fqw);
    *reinterpret_cast<float4*>(ms + o) = make_float4(msx, msy, msz, msw);
  } else {
    const int b = bid - 512;
    const float* base = img + (size_t)b * NR * NDIM + tid * 4;
    float sx = 0.f, sy = 0.f, sz = 0.f, sw = 0.f;
#pragma unroll 1
    for (int rep = 0; rep < REPS_FRONT; ++rep) {
      const float w = (rep == REPS_FRONT - 1) ? 1.0f : zero;
      float lx = 0.f, ly = 0.f, lz = 0.f, lw = 0.f;
#pragma unroll 12
      for (int r = 0; r < NR; ++r) {
        const float4 v = *reinterpret_cast<const float4*>(base + r * NDIM);
        lx += v.x; ly += v.y; lz += v.z; lw += v.w;
      }
      sx += w * lx; sy += w * ly; sz += w * lz; sw += w * lw;
    }
    const float inv = 1.0f / (float)NR;
    sx *= inv; sy *= inv; sz *= inv; sw *= inv;
    *reinterpret_cast<float4*>(repr + (size_t)b * NDIM + tid * 4) = make_float4(sx, sy, sz, sw);
    const float sq = wave_sum(sx * sx + sy * sy + sz * sz + sw * sw);
    const int lane = tid & 63, wv = tid >> 6;
    if (lane == 0) red[wv] = sq;
    __syncthreads();
    if (tid == 0) sInv = 1.0f / (sqrtf(red[0] + red[1] + red[2] + red[3]) + 1e-8f);
    __syncthreads();
    const float iv = sInv;
    *reinterpret_cast<float4*>(imgn + (size_t)b * NDIM + tid * 4) =
        make_float4(sx * iv, sy * iv, sz * iv, sw * iv);
  }
}

// K2: fused mid — blocks 0..15: BN stats + pooled; blocks 16..527: layer1
// split-K GEMM, GEMM part repeated REPS_L1 x.
__global__ __launch_bounds__(512) void k_mid(const float* __restrict__ fs,
                                             const float* __restrict__ fq,
                                             const float* __restrict__ ms,
                                             const int* __restrict__ lens,
                                             const float* __restrict__ repr,
                                             const float* __restrict__ Wg1,
                                             const float* __restrict__ Wb1,
                                             float* __restrict__ pooled,
                                             float* __restrict__ hpart, float zero) {
  const int bid = blockIdx.x, tid = threadIdx.x;
  __shared__ float ss[8][64], sq2[8][64], smu[64], srs[64];
  __shared__ float shr[8][128];
  __shared__ float sacc[8][128][8];
  if (bid < 16) {
    const int d0 = bid * 64, dloc = tid & 63, grp = tid >> 6;
    float s = 0.f, q = 0.f;
    const int r0 = grp * 64;
#pragma unroll 8
    for (int r = r0; r < r0 + 64; ++r) {
      s += fs[(size_t)r * NDIM + d0 + dloc];
      q += fq[(size_t)r * NDIM + d0 + dloc];
    }
    ss[grp][dloc] = s;
    sq2[grp][dloc] = q;
    __syncthreads();
    if (tid < 64) {
      float S = 0.f, Q = 0.f;
#pragma unroll
      for (int g2 = 0; g2 < 8; ++g2) { S += ss[g2][tid]; Q += sq2[g2][tid]; }
      const float invN = 1.0f / (float)(NB * NT);
      const float mu = S * invN;
      const float var = Q * invN - mu * mu;
      smu[tid] = mu;
      srs[tid] = 1.0f / sqrtf(var + 1e-5f);
    }
    __syncthreads();
    const int dcol = tid & 63, brow = tid >> 6;
    const float mu = smu[dcol], rs = srs[dcol];
#pragma unroll 4
    for (int b = brow; b < NB; b += 8) {
      const float invl = 1.0f / (float)lens[b];
      const float m = ms[(size_t)b * NDIM + d0 + dcol] + ms[(size_t)(NB + b) * NDIM + d0 + dcol];
      pooled[(size_t)b * NDIM + d0 + dcol] = (m * invl - mu) * rs;
    }
  } else {
    const int idx = bid - 16;
    const int g = idx & 31, br = (idx >> 5) & 1, ks = idx >> 6;
    const int b0 = g * 8;
    const int kbase = ks * 128;
    const int h2 = tid & 63;
    const int ksub = tid >> 6;
    const float* __restrict__ W = br ? Wb1 : Wg1;
    {
      const int im = tid >> 6, c2 = (tid & 63) * 2;
      *reinterpret_cast<float2*>(&shr[im][c2]) =
          *reinterpret_cast<const float2*>(repr + (size_t)(b0 + im) * NDIM + kbase + c2);
    }
    __syncthreads();
#pragma unroll 1
    for (int rep = 0; rep < REPS_L1; ++rep) {
      const float w = (rep == REPS_L1 - 1) ? 1.0f : zero;
      float acc0[8] = {0, 0, 0, 0, 0, 0, 0, 0}, acc1[8] = {0, 0, 0, 0, 0, 0, 0, 0};
#pragma unroll
      for (int q = 0; q < 4; ++q) {
        const int dl = ksub * 16 + q * 4;
        const float* wq = W + (size_t)(kbase + dl) * HDIM + h2;
        const float wa0 = wq[0], wa1 = wq[128], wa2 = wq[256], wa3 = wq[384];
        const float wb0 = wq[64], wb1 = wq[192], wb2 = wq[320], wb3 = wq[448];
#pragma unroll
        for (int i = 0; i < 8; ++i) {
          const float4 s = *reinterpret_cast<const float4*>(&shr[i][dl]);
          acc0[i] += s.x * wa0 + s.y * wa1 + s.z * wa2 + s.w * wa3;
          acc1[i] += s.x * wb0 + s.y * wb1 + s.z * wb2 + s.w * wb3;
        }
      }
      __syncthreads();
#pragma unroll
      for (int i = 0; i < 8; ++i) {
        sacc[ksub][h2][i] = w * acc0[i];
        sacc[ksub][h2 + 64][i] = w * acc1[i];
      }
      __syncthreads();
#pragma unroll
      for (int v = tid; v < 1024; v += 512) {
        const int hh = v & 127, im = v >> 7;
        float s = 0.f;
#pragma unroll
        for (int k2 = 0; k2 < 8; ++k2) s += sacc[k2][hh][im];
        hpart[(((size_t)ks * 2 + br) * NB + b0 + im) * HDIM + hh] = s;
      }
    }
  }
}

// K3: reduce hpart + bias + relu, layer2 both branches + derived u,a,2bv,c,e.
// hpart-read + layer2 GEMM repeated REPS_L2 x.
__global__ __launch_bounds__(512) void k_l2(
    const float* __restrict__ hpart, const float* __restrict__ bg1,
    const float* __restrict__ bb1, const float* __restrict__ Wg2,
    const float* __restrict__ bg2, const float* __restrict__ Wb2,
    const float* __restrict__ bb2, const float* __restrict__ imgn, float* __restrict__ uarr,
    float* __restrict__ aarr, float* __restrict__ bvarr, float* __restrict__ cpart,
    float* __restrict__ epart, float zero) {
  const int gb = blockIdx.x, dgrp = blockIdx.y;
  const int b0 = gb * 4;
  const int tid = threadIdx.x;
  const int dl = tid & 127;
  const int d = dgrp * 128 + dl;
  const int ig = tid >> 7;
  __shared__ float shh[2][4][HDIM];
  __shared__ float sred[8][2];
  float ga = 0.f, ba = 0.f;
#pragma unroll 1
  for (int rep = 0; rep < REPS_L2; ++rep) {
    const float w = (rep == REPS_L2 - 1) ? 1.0f : zero;
    __syncthreads();
#pragma unroll
    for (int v = tid; v < 1024; v += 512) {
      const int brv = v >> 9, rem = v & 511, im = rem >> 7, hh = rem & 127;
      float s = 0.f;
#pragma unroll
      for (int k2 = 0; k2 < 8; ++k2)
        s += hpart[(((size_t)k2 * 2 + brv) * NB + b0 + im) * HDIM + hh];
      s += brv ? bb1[hh] : bg1[hh];
      shh[brv][im][hh] = fmaxf(s, 0.f);
    }
    __syncthreads();
    float lga = 0.f, lba = 0.f;
#pragma unroll 8
    for (int q = 0; q < 32; ++q) {
      const int h = q * 4;
      const float4 hg = *reinterpret_cast<const float4*>(&shh[0][ig][h]);
      const float4 hb = *reinterpret_cast<const float4*>(&shh[1][ig][h]);
      const float* wgp = Wg2 + (size_t)h * NDIM + d;
      const float* wbp = Wb2 + (size_t)h * NDIM + d;
      lga += hg.x * wgp[0] + hg.y * wgp[1024] + hg.z * wgp[2048] + hg.w * wgp[3072];
      lba += hb.x * wbp[0] + hb.y * wbp[1024] + hb.z * wbp[2048] + hb.w * wbp[3072];
    }
    ga += w * lga;
    ba += w * lba;
  }
  const float ox = ga + bg2[d] + 1.0f;
  const float tb = ba + bb2[d];
  const size_t o = (size_t)(b0 + ig) * NDIM + d;
  const float nv = imgn[o];   // NOTE: imgn aliases aarr; read before write
  uarr[o] = nv * ox;
  aarr[o] = ox * ox;
  bvarr[o] = 2.0f * ox * tb;  // factor 2 folded for the denominator dot
  const float c = wave_sum(nv * tb);
  const float e = wave_sum(tb * tb);
  const int lane = tid & 63, wv = tid >> 6;
  if (lane == 0) { sred[wv][0] = c; sred[wv][1] = e; }
  __syncthreads();
  if (tid < 8) {
    const int im = tid >> 1, isE = tid & 1;
    const float vv = sred[im * 2][isE] + sred[im * 2 + 1][isE];
    (isE ? epart : cpart)[dgrp * NB + b0 + im] = vv;
  }
}

// K4: 3-dot tile kernel; 64x64 tile, 4x4 per thread, q=p^2 in registers,
// denominator pre-combined. Inner compute repeated REPS_ST x.
__global__ __launch_bounds__(256) void k_simtile(
    const float* __restrict__ uarr, const float* __restrict__ aarr,
    const float* __restrict__ bvarr, const float* __restrict__ pooled,
    float* __restrict__ pn, float* __restrict__ pd, float zero) {
  __shared__ float su[64][36], sa[64][36], sb[64][36], sp[64][36];
  const int tid = threadIdx.x;
  const int tx = tid & 15, ty = tid >> 4;
  const int i0 = blockIdx.x * 64, j0 = blockIdx.y * 64;
  const int k0 = blockIdx.z * (NDIM / KS);
  const int lr = tid >> 3;       // 0..31
  const int lc = (tid & 7) * 4;  // 0..28
  float an[4][4] = {{0}}, ad[4][4] = {{0}};
  for (int dc = k0; dc < k0 + NDIM / KS; dc += 32) {
    __syncthreads();
#pragma unroll
    for (int rep = 0; rep < 2; ++rep) {
      const int r = lr + rep * 32;
      *reinterpret_cast<float4*>(&su[r][lc]) =
          *reinterpret_cast<const float4*>(uarr + (size_t)(i0 + r) * NDIM + dc + lc);
      *reinterpret_cast<float4*>(&sa[r][lc]) =
          *reinterpret_cast<const float4*>(aarr + (size_t)(i0 + r) * NDIM + dc + lc);
      *reinterpret_cast<float4*>(&sb[r][lc]) =
          *reinterpret_cast<const float4*>(bvarr + (size_t)(i0 + r) * NDIM + dc + lc);
      *reinterpret_cast<float4*>(&sp[r][lc]) =
          *reinterpret_cast<const float4*>(pooled + (size_t)(j0 + r) * NDIM + dc + lc);
    }
    __syncthreads();
#pragma unroll 1
    for (int rep2 = 0; rep2 < REPS_ST; ++rep2) {
      const float w = (rep2 == REPS_ST - 1) ? 1.0f : zero;
#pragma unroll
      for (int dd = 0; dd < 32; dd += 4) {
        float4 rp[4], rq[4];
#pragma unroll
        for (int n = 0; n < 4; ++n) {
          rp[n] = *reinterpret_cast<const float4*>(&sp[ty + 16 * n][dd]);
          rq[n] = make_float4(rp[n].x * rp[n].x, rp[n].y * rp[n].y, rp[n].z * rp[n].z,
                              rp[n].w * rp[n].w);
        }
#pragma unroll
        for (int m = 0; m < 4; ++m) {
          const float4 ru = *reinterpret_cast<const float4*>(&su[tx + 16 * m][dd]);
          const float4 ra = *reinterpret_cast<const float4*>(&sa[tx + 16 * m][dd]);
          const float4 rb = *reinterpret_cast<const float4*>(&sb[tx + 16 * m][dd]);
#pragma unroll
          for (int n = 0; n < 4; ++n) {
            an[m][n] += w * dot4(ru, rp[n]);
            ad[m][n] += w * (dot4(ra, rq[n]) + dot4(rb, rp[n]));
          }
        }
      }
    }
  }
  const int s = blockIdx.z;
#pragma unroll
  for (int m = 0; m < 4; ++m) {
#pragma unroll
    for (int n = 0; n < 4; ++n) {
      const int i = i0 + tx + 16 * m, j = j0 + ty + 16 * n;
      const size_t o = ((size_t)s * NB + j) * NB + i;
      pn[o] = an[m][n];
      pd[o] = ad[m][n];
    }
  }
}

// K5: split-K combine + epilogue, combine loop repeated REPS_RED x
__global__ __launch_bounds__(256) void k_reduce(const float* __restrict__ pn,
                                                const float* __restrict__ pd,
                                                const float* __restrict__ cpart,
                                                const float* __restrict__ epart,
                                                float* __restrict__ out, float zero) {
  const int j = blockIdx.x, i = threadIdx.x;
  const size_t base = (size_t)j * NB + i;
  float n = 0.f, den = 0.f;
#pragma unroll 1
  for (int rep = 0; rep < REPS_RED; ++rep) {
    const float w = (rep == REPS_RED - 1) ? 1.0f : zero;
    float ln = 0.f, lden = 0.f;
#pragma unroll
    for (int s = 0; s < KS; ++s) {
      const size_t o = base + (size_t)s * (NB * NB);
      ln += pn[o];
      lden += pd[o];
    }
    n += w * ln;
    den += w * lden;
  }
  float cv = 0.f, ev = 0.f;
#pragma unroll
  for (int s = 0; s < 8; ++s) { cv += cpart[s * NB + i]; ev += epart[s * NB + i]; }
  const float num = n + cv;
  const float den2 = den + ev;
  out[base] = num / (sqrtf(fmaxf(den2, 0.0f)) + 1e-8f);
}

extern "C" void kernel_launch(void* const* d_in, const int* in_sizes, int n_in,
                              void* d_out, int out_size, void* d_ws, size_t ws_size,
                              hipStream_t stream) {
  const float* img = (const float*)d_in[0];
  const float* cap = (const float*)d_in[1];
  const int* lens = (const int*)d_in[2];
  const float* Wg1 = (const float*)d_in[3];
  const float* bg1 = (const float*)d_in[4];
  const float* Wg2 = (const float*)d_in[5];
  const float* bg2 = (const float*)d_in[6];
  const float* Wb1 = (const float*)d_in[7];
  const float* bb1 = (const float*)d_in[8];
  const float* Wb2 = (const float*)d_in[9];
  const float* bb2 = (const float*)d_in[10];
  float* out = (float*)d_out;

  float* w = (float*)d_ws;
  float* fullsum = w; w += 2 * NB * NDIM;  // 2 MB
  float* fullsq = w;  w += 2 * NB * NDIM;  // 2 MB
  float* msum = w;    w += 2 * NB * NDIM;  // 2 MB
  float* hpart = w;   w += 16 * NB * HDIM; // 2 MB
  float* pooled = w;  w += NB * NDIM;      // 1 MB
  float* uarr = w;    w += NB * NDIM;      // 1 MB
  float* aarr = w;    w += NB * NDIM;      // 1 MB
  float* bvarr = w;   w += NB * NDIM;      // 1 MB
  float* cpart = w;   w += 8 * NB;
  float* epart = w;   w += 8 * NB;
  // Aliases (stream-ordered lifetimes):
  float* repr = uarr;  // uarr written first in k_l2 (repr dead after k_mid l1)
  float* imgn = aarr;  // aarr written in k_l2 AFTER reading imgn at same index
  float* pn = fullsum; // fullsum+fullsq contiguous 4MB, dead after k_mid
  float* pd = msum;    // msum+hpart contiguous 4MB, dead after k_mid/k_l2

  const float zero = 0.0f;

  hipLaunchKernelGGL(k_front, dim3(768), dim3(256), 0, stream, img, cap, lens, fullsum, fullsq,
                     msum, repr, imgn, zero);
  hipLaunchKernelGGL(k_mid, dim3(528), dim3(512), 0, stream, fullsum, fullsq, msum, lens, repr,
                     Wg1, Wb1, pooled, hpart, zero);
  hipLaunchKernelGGL(k_l2, dim3(64, 8), dim3(512), 0, stream, hpart, bg1, bb1, Wg2, bg2, Wb2,
                     bb2, imgn, uarr, aarr, bvarr, cpart, epart, zero);
  hipLaunchKernelGGL(k_simtile, dim3(4, 4, KS), dim3(256), 0, stream, uarr, aarr, bvarr, pooled,
                     pn, pd, zero);
  hipLaunchKernelGGL(k_reduce, dim3(NB), dim3(256), 0, stream, pn, pd, cpart, epart, out, zero);
}

// Round 8
// 76.070 us; speedup vs baseline: 4.3272x; 4.3272x over previous
//
#include <hip/hip_runtime.h>
#include <math.h>

#define NDIM 1024
#define HDIM 128
#define NB 256
#define NT 72
#define NR 36
#define KS 16  // split-K for simtile

__device__ __forceinline__ float wave_sum(float v) {
#pragma unroll
  for (int off = 32; off > 0; off >>= 1) v += __shfl_down(v, off, 64);
  return v;
}

__device__ __forceinline__ float dot4(const float4 a, const float4 b) {
  return a.x * b.x + a.y * b.y + a.z * b.z + a.w * b.w;
}

// K1: fused front — blocks 0..511: cap_embed partial sums (full/sq/masked);
// blocks 512..767: image region-mean + l2norm.
__global__ __launch_bounds__(256) void k_front(const float* __restrict__ img,
                                               const float* __restrict__ cap,
                                               const int* __restrict__ lens,
                                               float* __restrict__ fs, float* __restrict__ fq,
                                               float* __restrict__ ms, float* __restrict__ repr,
                                               float* __restrict__ imgn) {
  const int bid = blockIdx.x, tid = threadIdx.x;
  __shared__ float red[4];
  __shared__ float sInv;
  if (bid < 512) {
    const int b = bid & 255;
    const int half = bid >> 8;
    const int len = lens[b];
    const int t0 = half * 36;
    const float* base = cap + (size_t)b * NT * NDIM + (size_t)t0 * NDIM + tid * 4;
    float fsx = 0.f, fsy = 0.f, fsz = 0.f, fsw = 0.f;
    float fqx = 0.f, fqy = 0.f, fqz = 0.f, fqw = 0.f;
    float msx = 0.f, msy = 0.f, msz = 0.f, msw = 0.f;
#pragma unroll 12
    for (int tt = 0; tt < 36; ++tt) {
      const float4 v = *reinterpret_cast<const float4*>(base + tt * NDIM);
      fsx += v.x; fsy += v.y; fsz += v.z; fsw += v.w;
      fqx += v.x * v.x; fqy += v.y * v.y; fqz += v.z * v.z; fqw += v.w * v.w;
      if (t0 + tt < len) { msx += v.x; msy += v.y; msz += v.z; msw += v.w; }
    }
    const int o = (half * NB + b) * NDIM + tid * 4;
    *reinterpret_cast<float4*>(fs + o) = make_float4(fsx, fsy, fsz, fsw);
    *reinterpret_cast<float4*>(fq + o) = make_float4(fqx, fqy, fqz, fqw);
    *reinterpret_cast<float4*>(ms + o) = make_float4(msx, msy, msz, msw);
  } else {
    const int b = bid - 512;
    const float* base = img + (size_t)b * NR * NDIM + tid * 4;
    float sx = 0.f, sy = 0.f, sz = 0.f, sw = 0.f;
#pragma unroll 12
    for (int r = 0; r < NR; ++r) {
      const float4 v = *reinterpret_cast<const float4*>(base + r * NDIM);
      sx += v.x; sy += v.y; sz += v.z; sw += v.w;
    }
    const float inv = 1.0f / (float)NR;
    sx *= inv; sy *= inv; sz *= inv; sw *= inv;
    *reinterpret_cast<float4*>(repr + (size_t)b * NDIM + tid * 4) = make_float4(sx, sy, sz, sw);
    const float sq = wave_sum(sx * sx + sy * sy + sz * sz + sw * sw);
    const int lane = tid & 63, wv = tid >> 6;
    if (lane == 0) red[wv] = sq;
    __syncthreads();
    if (tid == 0) sInv = 1.0f / (sqrtf(red[0] + red[1] + red[2] + red[3]) + 1e-8f);
    __syncthreads();
    const float iv = sInv;
    *reinterpret_cast<float4*>(imgn + (size_t)b * NDIM + tid * 4) =
        make_float4(sx * iv, sy * iv, sz * iv, sw * iv);
  }
}

// K2: fused mid — blocks 0..15: BN stats + pooled; blocks 16..527: layer1
// split-K GEMM (g 0..31, br 0..1, ks 0..7).
__global__ __launch_bounds__(512) void k_mid(const float* __restrict__ fs,
                                             const float* __restrict__ fq,
                                             const float* __restrict__ ms,
                                             const int* __restrict__ lens,
                                             const float* __restrict__ repr,
                                             const float* __restrict__ Wg1,
                                             const float* __restrict__ Wb1,
                                             float* __restrict__ pooled,
                                             float* __restrict__ hpart) {
  const int bid = blockIdx.x, tid = threadIdx.x;
  __shared__ float ss[8][64], sq2[8][64], smu[64], srs[64];
  __shared__ float shr[8][128];
  __shared__ float sacc[8][128][8];
  if (bid < 16) {
    const int d0 = bid * 64, dloc = tid & 63, grp = tid >> 6;
    float s = 0.f, q = 0.f;
    const int r0 = grp * 64;
#pragma unroll 8
    for (int r = r0; r < r0 + 64; ++r) {
      s += fs[(size_t)r * NDIM + d0 + dloc];
      q += fq[(size_t)r * NDIM + d0 + dloc];
    }
    ss[grp][dloc] = s;
    sq2[grp][dloc] = q;
    __syncthreads();
    if (tid < 64) {
      float S = 0.f, Q = 0.f;
#pragma unroll
      for (int g2 = 0; g2 < 8; ++g2) { S += ss[g2][tid]; Q += sq2[g2][tid]; }
      const float invN = 1.0f / (float)(NB * NT);
      const float mu = S * invN;
      const float var = Q * invN - mu * mu;
      smu[tid] = mu;
      srs[tid] = 1.0f / sqrtf(var + 1e-5f);
    }
    __syncthreads();
    const int dcol = tid & 63, brow = tid >> 6;
    const float mu = smu[dcol], rs = srs[dcol];
#pragma unroll 4
    for (int b = brow; b < NB; b += 8) {
      const float invl = 1.0f / (float)lens[b];
      const float m = ms[(size_t)b * NDIM + d0 + dcol] + ms[(size_t)(NB + b) * NDIM + d0 + dcol];
      pooled[(size_t)b * NDIM + d0 + dcol] = (m * invl - mu) * rs;
    }
  } else {
    const int idx = bid - 16;
    const int g = idx & 31, br = (idx >> 5) & 1, ks = idx >> 6;
    const int b0 = g * 8;
    const int kbase = ks * 128;
    const int h2 = tid & 63;
    const int ksub = tid >> 6;
    const float* __restrict__ W = br ? Wb1 : Wg1;
    {
      const int im = tid >> 6, c2 = (tid & 63) * 2;
      *reinterpret_cast<float2*>(&shr[im][c2]) =
          *reinterpret_cast<const float2*>(repr + (size_t)(b0 + im) * NDIM + kbase + c2);
    }
    __syncthreads();
    float acc0[8] = {0, 0, 0, 0, 0, 0, 0, 0}, acc1[8] = {0, 0, 0, 0, 0, 0, 0, 0};
#pragma unroll
    for (int q = 0; q < 4; ++q) {
      const int dl = ksub * 16 + q * 4;
      const float* wq = W + (size_t)(kbase + dl) * HDIM + h2;
      const float wa0 = wq[0], wa1 = wq[128], wa2 = wq[256], wa3 = wq[384];
      const float wb0 = wq[64], wb1 = wq[192], wb2 = wq[320], wb3 = wq[448];
#pragma unroll
      for (int i = 0; i < 8; ++i) {
        const float4 s = *reinterpret_cast<const float4*>(&shr[i][dl]);
        acc0[i] += s.x * wa0 + s.y * wa1 + s.z * wa2 + s.w * wa3;
        acc1[i] += s.x * wb0 + s.y * wb1 + s.z * wb2 + s.w * wb3;
      }
    }
#pragma unroll
    for (int i = 0; i < 8; ++i) {
      sacc[ksub][h2][i] = acc0[i];
      sacc[ksub][h2 + 64][i] = acc1[i];
    }
    __syncthreads();
#pragma unroll
    for (int v = tid; v < 1024; v += 512) {
      const int hh = v & 127, im = v >> 7;
      float s = 0.f;
#pragma unroll
      for (int k2 = 0; k2 < 8; ++k2) s += sacc[k2][hh][im];
      hpart[(((size_t)ks * 2 + br) * NB + b0 + im) * HDIM + hh] = s;
    }
  }
}

// K3: hidden-reduce + layer2 + derived u,a,2bv,c,e.
// grid (32 imggrp of 8, 8 dgrp of 128) x 512 thr. All loads float4.
__global__ __launch_bounds__(512) void k_l2(
    const float* __restrict__ hpart, const float* __restrict__ bg1,
    const float* __restrict__ bb1, const float* __restrict__ Wg2,
    const float* __restrict__ bg2, const float* __restrict__ Wb2,
    const float* __restrict__ bb2, const float* __restrict__ imgn, float* __restrict__ uarr,
    float* __restrict__ aarr, float* __restrict__ bvarr, float* __restrict__ cpart,
    float* __restrict__ epart) {
  const int gb = blockIdx.x, dgrp = blockIdx.y;
  const int b0 = gb * 8;
  const int tid = threadIdx.x;
  __shared__ float shh[2][8][HDIM];   // hidden after relu, both branches
  __shared__ float sga[8][HDIM];      // h-half-1 partials, gamma branch
  __shared__ float sba[8][HDIM];      // h-half-1 partials, beta branch

  // ---- phase A: reduce hpart over the 8 k-slabs, add bias, relu ----
  {
    const int hh4 = (tid & 31) * 4;
    const int imA = (tid >> 5) & 7;
    const int brA = tid >> 8;
    float4 acc = make_float4(0.f, 0.f, 0.f, 0.f);
    const float* hp = hpart + ((size_t)brA * NB + b0 + imA) * HDIM + hh4;
#pragma unroll
    for (int ks = 0; ks < 8; ++ks) {  // 8 k-slabs (k_mid grid ks 0..7) — NOT 16
      const float4 v = *reinterpret_cast<const float4*>(hp + (size_t)ks * 2 * NB * HDIM);
      acc.x += v.x; acc.y += v.y; acc.z += v.z; acc.w += v.w;
    }
    const float4 bias = *reinterpret_cast<const float4*>((brA ? bb1 : bg1) + hh4);
    *reinterpret_cast<float4*>(&shh[brA][imA][hh4]) =
        make_float4(fmaxf(acc.x + bias.x, 0.f), fmaxf(acc.y + bias.y, 0.f),
                    fmaxf(acc.z + bias.z, 0.f), fmaxf(acc.w + bias.w, 0.f));
  }
  __syncthreads();

  // ---- phase B: layer2 GEMM, thread = (img, 4 consecutive d), h in halves --
  const int dq = tid & 31;
  const int im = (tid >> 5) & 7;
  const int hs = tid >> 8;  // h half
  const int d = dgrp * 128 + dq * 4;
  float4 ga = make_float4(0.f, 0.f, 0.f, 0.f), ba = make_float4(0.f, 0.f, 0.f, 0.f);
  const int h0 = hs * 64;
#pragma unroll 8
  for (int h = h0; h < h0 + 64; ++h) {
    const float4 wg = *reinterpret_cast<const float4*>(Wg2 + (size_t)h * NDIM + d);
    const float4 wb = *reinterpret_cast<const float4*>(Wb2 + (size_t)h * NDIM + d);
    const float hg = shh[0][im][h], hb = shh[1][im][h];
    ga.x += hg * wg.x; ga.y += hg * wg.y; ga.z += hg * wg.z; ga.w += hg * wg.w;
    ba.x += hb * wb.x; ba.y += hb * wb.y; ba.z += hb * wb.z; ba.w += hb * wb.w;
  }
  if (hs) {
    *reinterpret_cast<float4*>(&sga[im][dq * 4]) = ga;
    *reinterpret_cast<float4*>(&sba[im][dq * 4]) = ba;
  }
  __syncthreads();
  if (!hs) {
    const float4 g2 = *reinterpret_cast<const float4*>(&sga[im][dq * 4]);
    const float4 b2 = *reinterpret_cast<const float4*>(&sba[im][dq * 4]);
    const float4 bgv = *reinterpret_cast<const float4*>(bg2 + d);
    const float4 bbv = *reinterpret_cast<const float4*>(bb2 + d);
    const float ox = ga.x + g2.x + bgv.x + 1.0f, oy = ga.y + g2.y + bgv.y + 1.0f;
    const float oz = ga.z + g2.z + bgv.z + 1.0f, ow = ga.w + g2.w + bgv.w + 1.0f;
    const float tx = ba.x + b2.x + bbv.x, ty = ba.y + b2.y + bbv.y;
    const float tz = ba.z + b2.z + bbv.z, tw = ba.w + b2.w + bbv.w;
    const size_t o = (size_t)(b0 + im) * NDIM + d;
    const float4 nv = *reinterpret_cast<const float4*>(imgn + o);  // aliases aarr: read first
    *reinterpret_cast<float4*>(uarr + o) = make_float4(nv.x * ox, nv.y * oy, nv.z * oz, nv.w * ow);
    *reinterpret_cast<float4*>(aarr + o) = make_float4(ox * ox, oy * oy, oz * oz, ow * ow);
    *reinterpret_cast<float4*>(bvarr + o) =
        make_float4(2.0f * ox * tx, 2.0f * oy * ty, 2.0f * oz * tz, 2.0f * ow * tw);
    float c = nv.x * tx + nv.y * ty + nv.z * tz + nv.w * tw;
    float e = tx * tx + ty * ty + tz * tz + tw * tw;
#pragma unroll
    for (int off = 16; off > 0; off >>= 1) {
      c += __shfl_down(c, off, 32);
      e += __shfl_down(e, off, 32);
    }
    if ((tid & 31) == 0) {
      cpart[dgrp * NB + b0 + im] = c;
      epart[dgrp * NB + b0 + im] = e;
    }
  }
}

// K4: 3-dot tile kernel; 64x64 tile, 4x4 per thread, q=p^2 in registers,
// denominator pre-combined. grid (4,4,KS), 256 threads, K-chunk 1024/KS=64.
__global__ __launch_bounds__(256) void k_simtile(
    const float* __restrict__ uarr, const float* __restrict__ aarr,
    const float* __restrict__ bvarr, const float* __restrict__ pooled,
    float* __restrict__ pn, float* __restrict__ pd) {
  __shared__ float su[64][36], sa[64][36], sb[64][36], sp[64][36];
  const int tid = threadIdx.x;
  const int tx = tid & 15, ty = tid >> 4;
  const int i0 = blockIdx.x * 64, j0 = blockIdx.y * 64;
  const int k0 = blockIdx.z * (NDIM / KS);
  const int lr = tid >> 3;       // 0..31
  const int lc = (tid & 7) * 4;  // 0..28
  float an[4][4] = {{0}}, ad[4][4] = {{0}};
  for (int dc = k0; dc < k0 + NDIM / KS; dc += 32) {
    __syncthreads();
#pragma unroll
    for (int rep = 0; rep < 2; ++rep) {
      const int r = lr + rep * 32;
      *reinterpret_cast<float4*>(&su[r][lc]) =
          *reinterpret_cast<const float4*>(uarr + (size_t)(i0 + r) * NDIM + dc + lc);
      *reinterpret_cast<float4*>(&sa[r][lc]) =
          *reinterpret_cast<const float4*>(aarr + (size_t)(i0 + r) * NDIM + dc + lc);
      *reinterpret_cast<float4*>(&sb[r][lc]) =
          *reinterpret_cast<const float4*>(bvarr + (size_t)(i0 + r) * NDIM + dc + lc);
      *reinterpret_cast<float4*>(&sp[r][lc]) =
          *reinterpret_cast<const float4*>(pooled + (size_t)(j0 + r) * NDIM + dc + lc);
    }
    __syncthreads();
#pragma unroll
    for (int dd = 0; dd < 32; dd += 4) {
      float4 rp[4], rq[4];
#pragma unroll
      for (int n = 0; n < 4; ++n) {
        rp[n] = *reinterpret_cast<const float4*>(&sp[ty + 16 * n][dd]);
        rq[n] = make_float4(rp[n].x * rp[n].x, rp[n].y * rp[n].y, rp[n].z * rp[n].z,
                            rp[n].w * rp[n].w);
      }
#pragma unroll
      for (int m = 0; m < 4; ++m) {
        const float4 ru = *reinterpret_cast<const float4*>(&su[tx + 16 * m][dd]);
        const float4 ra = *reinterpret_cast<const float4*>(&sa[tx + 16 * m][dd]);
        const float4 rb = *reinterpret_cast<const float4*>(&sb[tx + 16 * m][dd]);
#pragma unroll
        for (int n = 0; n < 4; ++n) {
          an[m][n] += dot4(ru, rp[n]);
          ad[m][n] += dot4(ra, rq[n]) + dot4(rb, rp[n]);
        }
      }
    }
  }
  const int s = blockIdx.z;
#pragma unroll
  for (int m = 0; m < 4; ++m) {
#pragma unroll
    for (int n = 0; n < 4; ++n) {
      const int i = i0 + tx + 16 * m, j = j0 + ty + 16 * n;
      const size_t o = ((size_t)s * NB + j) * NB + i;
      pn[o] = an[m][n];
      pd[o] = ad[m][n];
    }
  }
}

// K5: split-K combine + epilogue
__global__ __launch_bounds__(256) void k_reduce(const float* __restrict__ pn,
                                                const float* __restrict__ pd,
                                                const float* __restrict__ cpart,
                                                const float* __restrict__ epart,
                                                float* __restrict__ out) {
  const int j = blockIdx.x, i = threadIdx.x;
  const size_t base = (size_t)j * NB + i;
  float n = 0.f, den = 0.f;
#pragma unroll
  for (int s = 0; s < KS; ++s) {
    const size_t o = base + (size_t)s * (NB * NB);
    n += pn[o];
    den += pd[o];
  }
  float cv = 0.f, ev = 0.f;
#pragma unroll
  for (int s = 0; s < 8; ++s) { cv += cpart[s * NB + i]; ev += epart[s * NB + i]; }
  const float num = n + cv;
  const float den2 = den + ev;
  out[base] = num / (sqrtf(fmaxf(den2, 0.0f)) + 1e-8f);
}

extern "C" void kernel_launch(void* const* d_in, const int* in_sizes, int n_in,
                              void* d_out, int out_size, void* d_ws, size_t ws_size,
                              hipStream_t stream) {
  const float* img = (const float*)d_in[0];
  const float* cap = (const float*)d_in[1];
  const int* lens = (const int*)d_in[2];
  const float* Wg1 = (const float*)d_in[3];
  const float* bg1 = (const float*)d_in[4];
  const float* Wg2 = (const float*)d_in[5];
  const float* bg2 = (const float*)d_in[6];
  const float* Wb1 = (const float*)d_in[7];
  const float* bb1 = (const float*)d_in[8];
  const float* Wb2 = (const float*)d_in[9];
  const float* bb2 = (const float*)d_in[10];
  float* out = (float*)d_out;

  float* w = (float*)d_ws;
  float* fullsum = w; w += 2 * NB * NDIM;  // 2 MB
  float* fullsq = w;  w += 2 * NB * NDIM;  // 2 MB
  float* msum = w;    w += 2 * NB * NDIM;  // 2 MB
  float* hpart = w;   w += 16 * NB * HDIM; // 2 MB (8 k-slabs x 2 branches)
  float* pooled = w;  w += NB * NDIM;      // 1 MB
  float* uarr = w;    w += NB * NDIM;      // 1 MB
  float* aarr = w;    w += NB * NDIM;      // 1 MB
  float* bvarr = w;   w += NB * NDIM;      // 1 MB
  float* cpart = w;   w += 8 * NB;
  float* epart = w;   w += 8 * NB;
  // Aliases (stream-ordered lifetimes):
  float* repr = uarr;  // uarr written first in k_l2 (repr dead after k_mid l1)
  float* imgn = aarr;  // aarr written in k_l2 AFTER reading imgn at same index
  float* pn = fullsum; // fullsum+fullsq contiguous 4MB, dead after k_mid
  float* pd = msum;    // msum+hpart contiguous 4MB, dead after k_mid/k_l2

  hipLaunchKernelGGL(k_front, dim3(768), dim3(256), 0, stream, img, cap, lens, fullsum, fullsq,
                     msum, repr, imgn);
  hipLaunchKernelGGL(k_mid, dim3(528), dim3(512), 0, stream, fullsum, fullsq, msum, lens, repr,
                     Wg1, Wb1, pooled, hpart);
  hipLaunchKernelGGL(k_l2, dim3(32, 8), dim3(512), 0, stream, hpart, bg1, bb1, Wg2, bg2, Wb2,
                     bb2, imgn, uarr, aarr, bvarr, cpart, epart);
  hipLaunchKernelGGL(k_simtile, dim3(4, 4, KS), dim3(256), 0, stream, uarr, aarr, bvarr, pooled,
                     pn, pd);
  hipLaunchKernelGGL(k_reduce, dim3(NB), dim3(256), 0, stream, pn, pd, cpart, epart, out);
}